// Round 7
// baseline (35401.843 us; speedup 1.0000x reference)
//
#include <hip/hip_runtime.h>

// Persistent layer-pipelined GRU, f32. 256 blocks x 512 threads, 1 block/CU.
// Diagonal wavefront: macro-step m runs A(l0,t=m), A(l1,m-1), A(l2,m-2) in one
// phase (deps satisfied by previous macro-step's C phase), then fused C for all
// three layers. 2 grid barriers per macro-step (1028 total vs r6's 3072).
// Sweeps fused per activation stream: h0 read once -> {A(l0) h-side via LDS Wh0,
// A(l1) x-side via Wx1}; h1 -> {A(l1) h, A(l2) x}; h2 -> {A(l2) h, head}.
// Cross-block state (hT,rhT,barrier) via agent-scope relaxed atomics (sc1,
// MALL-coherent, no cache-nuking fences) — proven in r6.

struct GruParams {
  const float* x;            // (32, 512, 128)
  const float* Wx[3][3];     // [layer][gate z,r,g]
  const float* Wh[3][3];
  const float* bias[3][3];
  const float* Wout;         // (128, 1024)
  const float* bout;         // (128)
  float* hT;                 // [3][1024][32]  (k-major, b-minor)
  float* rhT;                // [3][1024][32]
  unsigned* bar;
  float* out;                // (B,S,O)
  float* outHid;             // (B,L,H)
};

#define WFLOATS 36864              // 9 slices * 4 rows * 1024
#define SFLOATS 3456
#define LDSB ((WFLOATS + SFLOATS) * 4)   // 161,280 B

extern __shared__ float lds[];

__device__ __forceinline__ float loadc(const float* p) {
  return __hip_atomic_load((float*)p, __ATOMIC_RELAXED, __HIP_MEMORY_SCOPE_AGENT);
}
__device__ __forceinline__ void storec(float* p, float v) {
  __hip_atomic_store(p, v, __ATOMIC_RELAXED, __HIP_MEMORY_SCOPE_AGENT);
}
__device__ __forceinline__ void fma4(float& acc, float o0, float o1, float o2,
                                     float o3, const float4 v) {
  acc += o0 * v.x; acc += o1 * v.y; acc += o2 * v.z; acc += o3 * v.w;
}

// Two-level barrier: 16 groups x 16 blocks, 128B-strided lines (r6-proven).
__device__ __forceinline__ void gridbar(unsigned* bar, unsigned phase, int bid) {
  __syncthreads();
  if (threadIdx.x == 0) {
    const int g = bid & 15;
    unsigned* grp   = bar + (g << 5);
    unsigned* root  = bar + 512;
    unsigned* go    = bar + 544;
    unsigned* grpGo = bar + 576 + (g << 5);
    const unsigned tgt = phase << 4;
    unsigned old = __hip_atomic_fetch_add(grp, 1u, __ATOMIC_RELAXED, __HIP_MEMORY_SCOPE_AGENT);
    if (old == tgt - 1u) {
      unsigned r = __hip_atomic_fetch_add(root, 1u, __ATOMIC_RELAXED, __HIP_MEMORY_SCOPE_AGENT);
      if (r == tgt - 1u)
        __hip_atomic_store(go, phase, __ATOMIC_RELAXED, __HIP_MEMORY_SCOPE_AGENT);
      while (__hip_atomic_load(go, __ATOMIC_RELAXED, __HIP_MEMORY_SCOPE_AGENT) < phase)
        __builtin_amdgcn_s_sleep(2);
      __hip_atomic_store(grpGo, phase, __ATOMIC_RELAXED, __HIP_MEMORY_SCOPE_AGENT);
    } else {
      while (__hip_atomic_load(grpGo, __ATOMIC_RELAXED, __HIP_MEMORY_SCOPE_AGENT) < phase)
        __builtin_amdgcn_s_sleep(2);
    }
  }
  __syncthreads();
}

// A-stage epilogue: reduce az/ar/ag over block, apply bias/sigmoid, emit rh.
__device__ __forceinline__ void reduceA(
    float* scratch, float (&az)[4], float (&ar)[4], float (&ag)[4],
    const float* bz, const float* br, const float* bg,
    const float* hTl, float* rhTl,
    int tid, int w, int b, int ks, int jbase,
    float& o_z, float& o_gx)
{
  #pragma unroll
  for (int jj = 0; jj < 4; ++jj) {
    az[jj] += __shfl_xor(az[jj], 32);
    ar[jj] += __shfl_xor(ar[jj], 32);
    ag[jj] += __shfl_xor(ag[jj], 32);
  }
  if (ks == 0) {
    #pragma unroll
    for (int jj = 0; jj < 4; ++jj) {
      scratch[w * 384 + (jj * 3 + 0) * 32 + b] = az[jj];
      scratch[w * 384 + (jj * 3 + 1) * 32 + b] = ar[jj];
      scratch[w * 384 + (jj * 3 + 2) * 32 + b] = ag[jj];
    }
  }
  __syncthreads();
  if (tid < 384) {
    float s = 0.f;
    #pragma unroll
    for (int ww = 0; ww < 8; ++ww) s += scratch[ww * 384 + tid];
    scratch[3072 + tid] = s;
  }
  __syncthreads();
  if (tid < 128) {
    const int jj = tid >> 5, bb = tid & 31;
    const int j = jbase + jj;
    const float zp = scratch[3072 + (jj * 3 + 0) * 32 + bb] + bz[j];
    const float rp = scratch[3072 + (jj * 3 + 1) * 32 + bb] + br[j];
    const float gp = scratch[3072 + (jj * 3 + 2) * 32 + bb] + bg[j];
    const float z = 1.f / (1.f + expf(-zp));
    const float r = 1.f / (1.f + expf(-rp));
    o_z  = z;
    o_gx = gp;
    storec(rhTl + (j << 5) + bb, r * loadc(hTl + (j << 5) + bb));
  }
  __syncthreads();
}

__global__ __launch_bounds__(512, 2) void gruPersist(GruParams p) {
  const int tid  = threadIdx.x;
  const int bid  = blockIdx.x;
  const int w    = tid >> 6;
  const int lane = tid & 63;
  const int b    = lane & 31;
  const int ks   = lane >> 5;
  const int jbase = bid << 2;
  float* scratch = lds + WFLOATS;

  // cache Wh slices in LDS
  for (int idx = tid; idx < WFLOATS; idx += 512) {
    const int slice = idx >> 12, rem = idx & 4095;
    const int l = slice / 3, g = slice - l * 3;
    lds[idx] = p.Wh[l][g][((size_t)jbase << 10) + rem];
  }
  __syncthreads();

  float* hT0 = p.hT;  float* hT1 = p.hT + 32768;  float* hT2 = p.hT + 65536;
  float* rh0 = p.rhT; float* rh1 = p.rhT + 32768; float* rh2 = p.rhT + 65536;
  const float* wz0 = lds;            const float* wr0 = lds + 4096;  const float* wg0 = lds + 8192;
  const float* wz1 = lds + 12288;    const float* wr1 = lds + 16384; const float* wg1 = lds + 20480;
  const float* wz2 = lds + 24576;    const float* wr2 = lds + 28672; const float* wg2 = lds + 32768;

  unsigned phase = 0;
  float my_z[3] = {0.f,0.f,0.f}, my_gx[3] = {0.f,0.f,0.f};

  for (int m = 0; m < 514; ++m) {
    const bool act0 = (m < 512);
    const bool act1 = (m >= 1 && m <= 512);
    const bool act2 = (m >= 2 && m <= 513);
    const int t0 = m, t1 = m - 1, t2 = m - 2, th = m - 3;

    // ================= phase 1: A(l0,t0) + A(l1,t1) + A(l2,t2) + head(th) ===
    float a0z[4] = {0,0,0,0}, a0r[4] = {0,0,0,0}, a0g[4] = {0,0,0,0};
    if (act0) {   // l0 x-side (K=128)
      const float* xb = p.x + ((size_t)b << 16) + ((size_t)t0 << 7);
      #pragma unroll
      for (int i = 0; i < 2; ++i) {
        const int k = (w << 4) + (i << 3) + (ks << 2);
        const float o0 = xb[k], o1 = xb[k+1], o2 = xb[k+2], o3 = xb[k+3];
        #pragma unroll
        for (int jj = 0; jj < 4; ++jj) {
          const size_t row = (size_t)(jbase + jj) * 128 + k;
          fma4(a0z[jj], o0,o1,o2,o3, *(const float4*)(p.Wx[0][0] + row));
          fma4(a0r[jj], o0,o1,o2,o3, *(const float4*)(p.Wx[0][1] + row));
          fma4(a0g[jj], o0,o1,o2,o3, *(const float4*)(p.Wx[0][2] + row));
        }
      }
    }
    // sweep1: h0 -> l0 z/r (LDS Wh0) + l1 z/r/g (Wx1)
    float a1z[4] = {0,0,0,0}, a1r[4] = {0,0,0,0}, a1g[4] = {0,0,0,0};
    #pragma unroll 2
    for (int i = 0; i < 16; ++i) {
      const int k = (w << 7) + (i << 3) + (ks << 2);
      const float o0 = loadc(hT0 + (k+0)*32 + b);
      const float o1 = loadc(hT0 + (k+1)*32 + b);
      const float o2 = loadc(hT0 + (k+2)*32 + b);
      const float o3 = loadc(hT0 + (k+3)*32 + b);
      #pragma unroll
      for (int jj = 0; jj < 4; ++jj) {
        const size_t row = ((size_t)(jbase + jj) << 10) + k;
        fma4(a0z[jj], o0,o1,o2,o3, *(const float4*)(wz0 + (jj<<10) + k));
        fma4(a0r[jj], o0,o1,o2,o3, *(const float4*)(wr0 + (jj<<10) + k));
        fma4(a1z[jj], o0,o1,o2,o3, *(const float4*)(p.Wx[1][0] + row));
        fma4(a1r[jj], o0,o1,o2,o3, *(const float4*)(p.Wx[1][1] + row));
        fma4(a1g[jj], o0,o1,o2,o3, *(const float4*)(p.Wx[1][2] + row));
      }
    }
    reduceA(scratch, a0z, a0r, a0g, p.bias[0][0], p.bias[0][1], p.bias[0][2],
            hT0, rh0, tid, w, b, ks, jbase, my_z[0], my_gx[0]);

    // sweep2: h1 -> l1 z/r (LDS Wh1) + l2 z/r/g (Wx2)
    float a2z[4] = {0,0,0,0}, a2r[4] = {0,0,0,0}, a2g[4] = {0,0,0,0};
    #pragma unroll 2
    for (int i = 0; i < 16; ++i) {
      const int k = (w << 7) + (i << 3) + (ks << 2);
      const float o0 = loadc(hT1 + (k+0)*32 + b);
      const float o1 = loadc(hT1 + (k+1)*32 + b);
      const float o2 = loadc(hT1 + (k+2)*32 + b);
      const float o3 = loadc(hT1 + (k+3)*32 + b);
      #pragma unroll
      for (int jj = 0; jj < 4; ++jj) {
        const size_t row = ((size_t)(jbase + jj) << 10) + k;
        fma4(a1z[jj], o0,o1,o2,o3, *(const float4*)(wz1 + (jj<<10) + k));
        fma4(a1r[jj], o0,o1,o2,o3, *(const float4*)(wr1 + (jj<<10) + k));
        fma4(a2z[jj], o0,o1,o2,o3, *(const float4*)(p.Wx[2][0] + row));
        fma4(a2r[jj], o0,o1,o2,o3, *(const float4*)(p.Wx[2][1] + row));
        fma4(a2g[jj], o0,o1,o2,o3, *(const float4*)(p.Wx[2][2] + row));
      }
    }
    reduceA(scratch, a1z, a1r, a1g, p.bias[1][0], p.bias[1][1], p.bias[1][2],
            hT1, rh1, tid, w, b, ks, jbase, my_z[1], my_gx[1]);

    // sweep3: h2 -> l2 z/r (LDS Wh2) + head (bid<128, o-row = bid)
    float ah = 0.f;
    #pragma unroll 2
    for (int i = 0; i < 16; ++i) {
      const int k = (w << 7) + (i << 3) + (ks << 2);
      const float o0 = loadc(hT2 + (k+0)*32 + b);
      const float o1 = loadc(hT2 + (k+1)*32 + b);
      const float o2 = loadc(hT2 + (k+2)*32 + b);
      const float o3 = loadc(hT2 + (k+3)*32 + b);
      #pragma unroll
      for (int jj = 0; jj < 4; ++jj) {
        fma4(a2z[jj], o0,o1,o2,o3, *(const float4*)(wz2 + (jj<<10) + k));
        fma4(a2r[jj], o0,o1,o2,o3, *(const float4*)(wr2 + (jj<<10) + k));
      }
      if (bid < 128)
        fma4(ah, o0,o1,o2,o3, *(const float4*)(p.Wout + ((size_t)bid << 10) + k));
    }
    reduceA(scratch, a2z, a2r, a2g, p.bias[2][0], p.bias[2][1], p.bias[2][2],
            hT2, rh2, tid, w, b, ks, jbase, my_z[2], my_gx[2]);

    if (m >= 3) {   // head for t=th (h2(th) finalized at macro-step m-1)
      ah += __shfl_xor(ah, 32);
      if (bid < 128 && ks == 0) scratch[w * 32 + b] = ah;
      __syncthreads();
      if (bid < 128 && tid < 32) {
        float s = 0.f;
        #pragma unroll
        for (int ww = 0; ww < 8; ++ww) s += scratch[ww * 32 + tid];
        p.out[((size_t)tid << 16) + ((size_t)th << 7) + bid] = s + p.bout[bid];
      }
      __syncthreads();
    }

    ++phase; gridbar(p.bar, phase, bid);

    // ================= phase 2: fused C for l0,l1,l2 =======================
    float c0[4] = {0,0,0,0}, c1[4] = {0,0,0,0}, c2[4] = {0,0,0,0};
    #pragma unroll 2
    for (int i = 0; i < 16; ++i) {
      const int k = (w << 7) + (i << 3) + (ks << 2);
      float r0_[4], r1_[4], r2_[4];
      #pragma unroll
      for (int q = 0; q < 4; ++q) {
        r0_[q] = loadc(rh0 + (k+q)*32 + b);
        r1_[q] = loadc(rh1 + (k+q)*32 + b);
        r2_[q] = loadc(rh2 + (k+q)*32 + b);
      }
      #pragma unroll
      for (int jj = 0; jj < 4; ++jj) {
        fma4(c0[jj], r0_[0],r0_[1],r0_[2],r0_[3], *(const float4*)(wg0 + (jj<<10) + k));
        fma4(c1[jj], r1_[0],r1_[1],r1_[2],r1_[3], *(const float4*)(wg1 + (jj<<10) + k));
        fma4(c2[jj], r2_[0],r2_[1],r2_[2],r2_[3], *(const float4*)(wg2 + (jj<<10) + k));
      }
    }
    #pragma unroll
    for (int jj = 0; jj < 4; ++jj) {
      c0[jj] += __shfl_xor(c0[jj], 32);
      c1[jj] += __shfl_xor(c1[jj], 32);
      c2[jj] += __shfl_xor(c2[jj], 32);
    }
    if (ks == 0) {
      #pragma unroll
      for (int jj = 0; jj < 4; ++jj) {
        scratch[w * 384 + (0 * 4 + jj) * 32 + b] = c0[jj];
        scratch[w * 384 + (1 * 4 + jj) * 32 + b] = c1[jj];
        scratch[w * 384 + (2 * 4 + jj) * 32 + b] = c2[jj];
      }
    }
    __syncthreads();
    if (tid < 384) {
      float s = 0.f;
      #pragma unroll
      for (int ww = 0; ww < 8; ++ww) s += scratch[ww * 384 + tid];
      scratch[3072 + tid] = s;
    }
    __syncthreads();
    if (tid < 128) {
      const int jj = tid >> 5, bb = tid & 31;
      const int j = jbase + jj;
      if (act0) {
        const float g = tanhf(scratch[3072 + (0*4 + jj)*32 + bb] + my_gx[0]);
        const float hp = loadc(hT0 + (j << 5) + bb);
        const float hn = my_z[0] * hp + (1.f - my_z[0]) * g;
        storec(hT0 + (j << 5) + bb, hn);
        if (t0 == 511) p.outHid[bb * 3072 + j] = hn;
      }
      if (act1) {
        const float g = tanhf(scratch[3072 + (1*4 + jj)*32 + bb] + my_gx[1]);
        const float hp = loadc(hT1 + (j << 5) + bb);
        const float hn = my_z[1] * hp + (1.f - my_z[1]) * g;
        storec(hT1 + (j << 5) + bb, hn);
        if (t1 == 511) p.outHid[bb * 3072 + 1024 + j] = hn;
      }
      if (act2) {
        const float g = tanhf(scratch[3072 + (2*4 + jj)*32 + bb] + my_gx[2]);
        const float hp = loadc(hT2 + (j << 5) + bb);
        const float hn = my_z[2] * hp + (1.f - my_z[2]) * g;
        storec(hT2 + (j << 5) + bb, hn);
        if (t2 == 511) p.outHid[bb * 3072 + 2048 + j] = hn;
      }
    }
    __syncthreads();
    ++phase; gridbar(p.bar, phase, bid);
  } // m

  // final head: t=511 (h2(511) finalized at the last C phase)
  {
    float ah = 0.f;
    if (bid < 128) {
      #pragma unroll 2
      for (int i = 0; i < 16; ++i) {
        const int k = (w << 7) + (i << 3) + (ks << 2);
        const float o0 = loadc(hT2 + (k+0)*32 + b);
        const float o1 = loadc(hT2 + (k+1)*32 + b);
        const float o2 = loadc(hT2 + (k+2)*32 + b);
        const float o3 = loadc(hT2 + (k+3)*32 + b);
        fma4(ah, o0,o1,o2,o3, *(const float4*)(p.Wout + ((size_t)bid << 10) + k));
      }
      ah += __shfl_xor(ah, 32);
      if (ks == 0) scratch[w * 32 + b] = ah;
    }
    __syncthreads();
    if (bid < 128 && tid < 32) {
      float s = 0.f;
      #pragma unroll
      for (int ww = 0; ww < 8; ++ww) s += scratch[ww * 32 + tid];
      p.out[((size_t)tid << 16) + ((size_t)511 << 7) + bid] = s + p.bout[bid];
    }
  }
}

// Zero hT, rhT, barrier region (ws poisoned 0xAA before every launch).
__global__ void initWs(float* ws, unsigned* bar) {
  const int i = blockIdx.x * 1024 + threadIdx.x;
  if (i < 196608) ws[i] = 0.f;
  if (i < 2048) bar[i] = 0u;
}

extern "C" void kernel_launch(void* const* d_in, const int* in_sizes, int n_in,
                              void* d_out, int out_size, void* d_ws, size_t ws_size,
                              hipStream_t stream)
{
  GruParams P;
  P.x = (const float*)d_in[0];
  P.Wx[0][0] = (const float*)d_in[1];  P.Wh[0][0] = (const float*)d_in[2];
  P.bias[0][0] = (const float*)d_in[3];
  P.Wx[0][1] = (const float*)d_in[4];  P.Wh[0][1] = (const float*)d_in[5];
  P.bias[0][1] = (const float*)d_in[6];
  P.Wx[0][2] = (const float*)d_in[7];  P.Wh[0][2] = (const float*)d_in[8];
  P.bias[0][2] = (const float*)d_in[9];
  for (int l = 1; l < 3; ++l) {
    const size_t off = (size_t)(l - 1) * 1048576;
    const size_t ob  = (size_t)(l - 1) * 1024;
    P.Wx[l][0] = (const float*)d_in[10] + off; P.Wh[l][0] = (const float*)d_in[11] + off;
    P.bias[l][0] = (const float*)d_in[12] + ob;
    P.Wx[l][1] = (const float*)d_in[13] + off; P.Wh[l][1] = (const float*)d_in[14] + off;
    P.bias[l][1] = (const float*)d_in[15] + ob;
    P.Wx[l][2] = (const float*)d_in[16] + off; P.Wh[l][2] = (const float*)d_in[17] + off;
    P.bias[l][2] = (const float*)d_in[18] + ob;
  }
  P.Wout = (const float*)d_in[19];
  P.bout = (const float*)d_in[20];

  float* ws = (float*)d_ws;
  P.hT  = ws;                          // 3*32768
  P.rhT = ws + 98304;                  // 3*32768
  P.bar = (unsigned*)(ws + 196608);    // 2048 uints
  P.out = (float*)d_out;
  P.outHid = P.out + 2097152;

  hipFuncSetAttribute(reinterpret_cast<const void*>(gruPersist),
                      hipFuncAttributeMaxDynamicSharedMemorySize, LDSB);

  initWs<<<192, 1024, 0, stream>>>(ws, P.bar);
  gruPersist<<<256, 512, LDSB, stream>>>(P);
}